// Round 9
// baseline (471.613 us; speedup 1.0000x reference)
//
#include <hip/hip_runtime.h>
#include <hip/hip_cooperative_groups.h>
#include <math.h>

namespace cg = cooperative_groups;

#define NM 131072
#define PP 256
#define BB 32
#define INF_F 3.0e38f

// mesh grid: 64x64 cells over [0,1)^2, expected 32 pts/cell
#define GM   64
#define GM2  (GM * GM)
#define CAPM 96
// pivot grid: 16x16 cells, expected 1 pivot/cell
#define GP   16
#define GP2  (GP * GP)
#define CAPP 8

typedef unsigned long long u64;

// Packed key: (float-bits of d << 32) | idx. d >= 0 so u32(d) ordering == float
// ordering; u64 ascending == (d asc, idx asc) == exact lax.top_k tie-break.
__device__ __forceinline__ u64 packkey(float d, int i) {
  return ((u64)__float_as_uint(d) << 32) | (unsigned)i;
}

// Branchless sorted insert into (k0<=k1<=k2).
__device__ __forceinline__ void ins3k(u64 k, u64& k0, u64& k1, u64& k2) {
  bool l0 = k < k0, l1 = k < k1, l2 = k < k2;
  k2 = l1 ? k1 : (l2 ? k : k2);
  k1 = l0 ? k0 : (l1 ? k : k1);
  k0 = l0 ? k : k0;
}

// Exact-fp32 distance matching the reference's (a-b)^2 + (c-d)^2 (no fma contraction).
__device__ __forceinline__ float dist2(float ax, float ay, float bx, float by) {
  float dx = ax - bx, dy = ay - by;
  return __fadd_rn(__fmul_rn(dx, dx), __fmul_rn(dy, dy));
}

// Per-phase LDS views over one 32 KB block (max phase = interp's 2048 float4).
union SMem {
  struct { u64 sk[PP * 3]; u64 g3[3]; int sdone; } a;                       // knnA: ~6.2 KB
  struct { float spx[PP], spy[PP]; unsigned scnt[GP2]; int sbuf[GP2 * CAPP]; } b; // knnB: 11 KB
  struct { float qs[2][8][64]; float ys[2][8][3]; } g;                      // gather: 4.3 KB
  struct { float4 sK[PP * 5]; float4 sY[PP]; } at;                          // attn: 24 KB
  struct { float4 sy[8 * PP]; } ip;                                         // interp: 32 KB
};

// ---------------- single cooperative megakernel: 512 blocks x 256 threads ----------------
// R8 post-mortem: wreg[64] spilled to scratch (VGPR_Count=52) -> 67M scratch
// loads -> ~300 us of VMEM-issue stall (VALUBusy 6.5%). P2 is rewritten to
// stream W with 8 named accumulators (no per-thread array => nothing to spill).
// Residual discovery: total-mega = ~120 us harness-fixed tax, so the
// controllable budget is kernel time alone.
__global__ __launch_bounds__(256, 2)
void mega(const float* __restrict__ node, const float* __restrict__ mesh,
          const float* __restrict__ piv, const float* __restrict__ gamma,
          const float* __restrict__ beta, const float* __restrict__ Wf,
          const float* __restrict__ bf, const float* __restrict__ Wp,
          const float* __restrict__ bp, const float* __restrict__ ipw,
          const float* __restrict__ ipb, float* __restrict__ out,
          float* __restrict__ ws) {
  cg::grid_group grid = cg::this_grid();
  const int blk = blockIdx.x;          // 0..511
  const int t = threadIdx.x;           // 0..255
  __shared__ SMem sm;

  // workspace layout
  unsigned* cntM = (unsigned*)ws;                      // 4096
  unsigned* cntP = cntM + 4096;                        // 256
  unsigned* ovfc = cntP + 256;                         // 2 (pad to 4608)
  float* bufM = ws + 4608;                             // GM2*CAPM*3
  int*   bufP = (int*)(bufM + (size_t)GM2 * CAPM * 3); // 2048
  float* ovfM = (float*)(bufP + GP2 * CAPP);           // NM*3
  int*   ovfP = (int*)(ovfM + (size_t)NM * 3);         // 256
  float* wA   = (float*)(ovfP + PP);                   // 768
  int*   idxA = (int*)(wA + PP * 3);                   // 768
  float* y    = (float*)(idxA + PP * 3);               // BB*PP*3
  float* Qh   = y + BB * PP * 3;                       // BB*4*PP*16
  float* Kh   = Qh + BB * PP * 64;
  float* y2   = Kh + BB * PP * 64;                     // BB*PP*4 (float4-padded)
  float4* wB4   = (float4*)(y2 + BB * PP * 4);         // NM
  int4*   idxB4 = (int4*)(wB4 + NM);                   // NM

  // ---------------- PZ: zero counters + y2 ----------------
  {
    const int idx = blk * 256 + t;
    if (idx < BB * PP * 4) y2[idx] = 0.f;
    if (idx < 4096) cntM[idx] = 0u;
    if (idx < GP2) cntP[idx] = 0u;
    if (idx < 2) ovfc[idx] = 0u;
  }
  grid.sync();

  // ---------------- P0: build buckets ----------------
  {
    const int g = blk * 256 + t;                       // exactly covers NM
    float2 mp = ((const float2*)mesh)[g];
    int cx = min((int)(mp.x * GM), GM - 1);
    int cy = min((int)(mp.y * GM), GM - 1);
    int c = cy * GM + cx;
    unsigned s = atomicAdd(&cntM[c], 1u);
    if (s < CAPM) {
      float* d = bufM + (size_t)(c * CAPM + s) * 3;
      d[0] = mp.x; d[1] = mp.y; ((int*)d)[2] = g;
    } else {
      unsigned o = atomicAdd(&ovfc[0], 1u);            // ovfM sized NM: never drops
      float* d = ovfM + (size_t)o * 3;
      d[0] = mp.x; d[1] = mp.y; ((int*)d)[2] = g;
    }
    if (blk == 0) {
      const int p = t;                                 // 256 pivots
      float2 pv = ((const float2*)piv)[p];
      int px = min((int)(pv.x * GP), GP - 1);
      int py = min((int)(pv.y * GP), GP - 1);
      int pc = py * GP + px;
      unsigned ps = atomicAdd(&cntP[pc], 1u);
      if (ps < CAPP) bufP[pc * CAPP + ps] = p;
      else { unsigned o = atomicAdd(&ovfc[1], 1u); ovfP[o] = p; }
    }
  }
  grid.sync();

  // ---------------- P1: knnA (blocks 0-255) || knnB (blocks 256-511, 2 tiles) ----------------
  if (blk < 256) {
    const int p = blk;
    const float2 pv = ((const float2*)piv)[p];
    const int cx = min((int)(pv.x * GM), GM - 1);
    const int cy = min((int)(pv.y * GM), GM - 1);

    u64 b0 = ~0ull, b1 = ~0ull, b2 = ~0ull;
    {
      int x0 = max(cx - 1, 0), x1 = min(cx + 1, GM - 1);
      int y0 = max(cy - 1, 0), y1 = min(cy + 1, GM - 1);
      for (int yy = y0; yy <= y1; ++yy) {
        int cb = yy * GM + x0;
        int tot = (x1 - x0 + 1) * CAPM;
        for (int s = t; s < tot; s += 256) {
          int ci = s / CAPM, j = s - ci * CAPM;
          int c = cb + ci;
          if (j < (int)min(cntM[c], (unsigned)CAPM)) {
            const float* cp = bufM + (size_t)(c * CAPM + j) * 3;
            float d = dist2(pv.x, pv.y, cp[0], cp[1]);
            ins3k(packkey(d, ((const int*)cp)[2]), b0, b1, b2);
          }
        }
      }
      int no = (int)ovfc[0];
      for (int j = t; j < no; j += 256) {
        const float* cp = ovfM + (size_t)j * 3;
        float d = dist2(pv.x, pv.y, cp[0], cp[1]);
        ins3k(packkey(d, ((const int*)cp)[2]), b0, b1, b2);
      }
    }

    int R = 1;
    u64 p0 = ~0ull, p1 = ~0ull, p2 = ~0ull;
    while (true) {
      sm.a.sk[t * 3 + 0] = b0; sm.a.sk[t * 3 + 1] = b1; sm.a.sk[t * 3 + 2] = b2;
      __syncthreads();
      if (t < 32) {
        u64 e0 = ~0ull, e1 = ~0ull, e2 = ~0ull;
#pragma unroll
        for (int s = 0; s < 8; ++s) {
          int o = (t + 32 * s) * 3;
          ins3k(sm.a.sk[o], e0, e1, e2); ins3k(sm.a.sk[o + 1], e0, e1, e2); ins3k(sm.a.sk[o + 2], e0, e1, e2);
        }
        sm.a.sk[t * 3] = e0; sm.a.sk[t * 3 + 1] = e1; sm.a.sk[t * 3 + 2] = e2;
      }
      __syncthreads();
      if (t == 0) {
        u64 e0 = p0, e1 = p1, e2 = p2;
        for (int s = 0; s < 32; ++s) {
          ins3k(sm.a.sk[s * 3], e0, e1, e2); ins3k(sm.a.sk[s * 3 + 1], e0, e1, e2); ins3k(sm.a.sk[s * 3 + 2], e0, e1, e2);
        }
        sm.a.g3[0] = e0; sm.a.g3[1] = e1; sm.a.g3[2] = e2;
        float d2f = __uint_as_float((unsigned)(e2 >> 32));
        float md = (float)R * (1.0f / GM);
        sm.a.sdone = (md * md > d2f) ? 1 : 0;          // NaN => false => expand
      }
      __syncthreads();
      if (sm.a.sdone) break;
      p0 = sm.a.g3[0]; p1 = sm.a.g3[1]; p2 = sm.a.g3[2];
      b0 = b1 = b2 = ~0ull;
      R += 1;
      int x0 = max(cx - R, 0), x1 = min(cx + R, GM - 1);
      for (int pass = 0; pass < 2; ++pass) {
        int yy = pass ? cy + R : cy - R;
        if (yy < 0 || yy > GM - 1) continue;
        int cb = yy * GM + x0;
        int tot = (x1 - x0 + 1) * CAPM;
        for (int s = t; s < tot; s += 256) {
          int ci = s / CAPM, j = s - ci * CAPM;
          int c = cb + ci;
          if (j < (int)min(cntM[c], (unsigned)CAPM)) {
            const float* cp = bufM + (size_t)(c * CAPM + j) * 3;
            float d = dist2(pv.x, pv.y, cp[0], cp[1]);
            ins3k(packkey(d, ((const int*)cp)[2]), b0, b1, b2);
          }
        }
      }
      int yy0 = max(cy - R + 1, 0), yy1 = min(cy + R - 1, GM - 1);
      for (int pass = 0; pass < 2; ++pass) {
        int xx = pass ? cx + R : cx - R;
        if (xx < 0 || xx > GM - 1) continue;
        int tot = (yy1 - yy0 + 1) * CAPM;
        for (int s = t; s < tot; s += 256) {
          int ri = s / CAPM, j = s - ri * CAPM;
          int c = (yy0 + ri) * GM + xx;
          if (j < (int)min(cntM[c], (unsigned)CAPM)) {
            const float* cp = bufM + (size_t)(c * CAPM + j) * 3;
            float d = dist2(pv.x, pv.y, cp[0], cp[1]);
            ins3k(packkey(d, ((const int*)cp)[2]), b0, b1, b2);
          }
        }
      }
      __syncthreads();
    }
    if (t == 0) {
#pragma unroll
      for (int k = 0; k < 3; ++k) {
        u64 e = sm.a.g3[k];
        float d = __uint_as_float((unsigned)(e >> 32));
        wA[p * 3 + k] = 1.0f / fmaxf(d, 1e-16f);
        idxA[p * 3 + k] = (int)(unsigned)(e & 0xffffffffu);
      }
    }
  } else {
    {
      float2 pvv = ((const float2*)piv)[t];
      sm.b.spx[t] = pvv.x; sm.b.spy[t] = pvv.y;
      sm.b.scnt[t] = cntP[t];
      for (int j = t; j < GP2 * CAPP; j += 256) sm.b.sbuf[j] = bufP[j];
    }
    __syncthreads();

    for (int rep = 0; rep < 2; ++rep) {
      const int m = (blk - 256 + rep * 256) * 256 + t;
      const float2 mv = ((const float2*)mesh)[m];
      const int cx = min((int)(mv.x * GP), GP - 1);
      const int cy = min((int)(mv.y * GP), GP - 1);
      u64 k0 = ~0ull, k1 = ~0ull, k2 = ~0ull;

      {  // rings 0..2 (5x5 clamped)
        int x0 = max(cx - 2, 0), x1 = min(cx + 2, GP - 1);
        int y0 = max(cy - 2, 0), y1 = min(cy + 2, GP - 1);
        for (int yy = y0; yy <= y1; ++yy)
          for (int xx = x0; xx <= x1; ++xx) {
            int c = yy * GP + xx;
            int n = (int)min(sm.b.scnt[c], (unsigned)CAPP);
            for (int j = 0; j < n; ++j) {
              int qq = sm.b.sbuf[c * CAPP + j];
              float d = dist2(mv.x, mv.y, sm.b.spx[qq], sm.b.spy[qq]);
              ins3k(packkey(d, qq), k0, k1, k2);
            }
          }
        int no = (int)ovfc[1];
        for (int j = 0; j < no; ++j) {
          int qq = ovfP[j];
          float d = dist2(mv.x, mv.y, sm.b.spx[qq], sm.b.spy[qq]);
          ins3k(packkey(d, qq), k0, k1, k2);
        }
      }
      int R = 2;
      while (true) {
        float d2f = __uint_as_float((unsigned)(k2 >> 32));
        float md = (float)R * (1.0f / GP);
        if (md * md > d2f) break;                      // NaN => expand
        R += 1;
        if (R >= 2 * GP) break;                        // safety
        int x0 = max(cx - R, 0), x1 = min(cx + R, GP - 1);
        for (int pass = 0; pass < 2; ++pass) {
          int yy = pass ? cy + R : cy - R;
          if (yy < 0 || yy > GP - 1) continue;
          for (int xx = x0; xx <= x1; ++xx) {
            int c = yy * GP + xx;
            int n = (int)min(sm.b.scnt[c], (unsigned)CAPP);
            for (int j = 0; j < n; ++j) {
              int qq = sm.b.sbuf[c * CAPP + j];
              float d = dist2(mv.x, mv.y, sm.b.spx[qq], sm.b.spy[qq]);
              ins3k(packkey(d, qq), k0, k1, k2);
            }
          }
        }
        int yy0 = max(cy - R + 1, 0), yy1 = min(cy + R - 1, GP - 1);
        for (int pass = 0; pass < 2; ++pass) {
          int xx = pass ? cx + R : cx - R;
          if (xx < 0 || xx > GP - 1) continue;
          for (int yy = yy0; yy <= yy1; ++yy) {
            int c = yy * GP + xx;
            int n = (int)min(sm.b.scnt[c], (unsigned)CAPP);
            for (int j = 0; j < n; ++j) {
              int qq = sm.b.sbuf[c * CAPP + j];
              float d = dist2(mv.x, mv.y, sm.b.spx[qq], sm.b.spy[qq]);
              ins3k(packkey(d, qq), k0, k1, k2);
            }
          }
        }
      }

      float d0 = __uint_as_float((unsigned)(k0 >> 32));
      float d1 = __uint_as_float((unsigned)(k1 >> 32));
      float d2v = __uint_as_float((unsigned)(k2 >> 32));
      float w0 = 1.0f / fmaxf(d0, 1e-16f);
      float w1 = 1.0f / fmaxf(d1, 1e-16f);
      float w2 = 1.0f / fmaxf(d2v, 1e-16f);
      float inv = 1.0f / (w0 + w1 + w2);
      wB4[m] = make_float4(w0, w1, w2, inv);
      idxB4[m] = make_int4((int)(unsigned)(k0 & 0xffffffffu),
                           (int)(unsigned)(k1 & 0xffffffffu),
                           (int)(unsigned)(k2 & 0xffffffffu), 0);
    }
  }
  grid.sync();

  // ---------------- P2: gather+LN + q/Q/K, streamed-W (no wreg array) ----------------
  // R8 fix: 8 named accumulators; W4[j] loaded once and applied to all 8 rows
  // via uniform-address LDS float4 broadcasts of qs. Nothing to spill.
  {
    const int hi = t >> 7, tl = t & 127;
    const int ob = 2 * blk + hi;                       // old blockIdx in [0,1024)
    const int b = ob >> 5;
    const int ptile = (ob & 31) * 8;
    float (*qs)[64] = sm.g.qs[hi];
    float (*ys)[3] = sm.g.ys[hi];

    if (tl < 8) {
      const int p = ptile + tl;
      const float g0 = gamma[0], g1 = gamma[1], g2 = gamma[2];
      const float be0 = beta[0], be1 = beta[1], be2 = beta[2];
      float num0 = 0.f, num1 = 0.f, num2 = 0.f, den = 0.f;
#pragma unroll
      for (int k = 0; k < 3; ++k) {
        int idx = idxA[p * 3 + k];
        float w = wA[p * 3 + k];
        const float* r = node + ((size_t)b * NM + idx) * 3;
        float a0 = r[0], a1 = r[1], a2 = r[2];
        float mu = (a0 + a1 + a2) * (1.0f / 3.0f);
        float e0 = a0 - mu, e1 = a1 - mu, e2 = a2 - mu;
        float var = (e0 * e0 + e1 * e1 + e2 * e2) * (1.0f / 3.0f);
        float sc = 1.0f / sqrtf(var + 1e-5f);
        num0 += (e0 * sc * g0 + be0) * w;
        num1 += (e1 * sc * g1 + be1) * w;
        num2 += (e2 * sc * g2 + be2) * w;
        den += w;
      }
      float o0 = num0 / den, o1 = num1 / den, o2 = num2 / den;
      ys[tl][0] = o0; ys[tl][1] = o1; ys[tl][2] = o2;
      float* yr = y + (b * PP + p) * 3;
      yr[0] = o0; yr[1] = o1; yr[2] = o2;              // attn stages y from global
    }
    __syncthreads();

    const int e = tl & 63;
    const int half = tl >> 6;                          // 0 -> Q, 1 -> K
    {
      float wf0 = Wf[e * 3], wf1 = Wf[e * 3 + 1], wf2 = Wf[e * 3 + 2];
      float wp0 = Wp[e * 2], wp1 = Wp[e * 2 + 1];
      float cst = bf[e] + bp[e];
      for (int r = half; r < 8; r += 2) {
        int p = ptile + r;
        float pe = piv[2 * p] * wp0 + piv[2 * p + 1] * wp1;
        qs[r][e] = ys[r][0] * wf0 + ys[r][1] * wf1 + ys[r][2] * wf2 + cst + pe;
      }
    }
    __syncthreads();

    const int row = half * 64 + e;
    const float4* W4 = (const float4*)(ipw + row * 64);
    const float bias = ipb[row];
    float a0 = bias, a1 = bias, a2 = bias, a3 = bias;
    float a4 = bias, a5 = bias, a6 = bias, a7 = bias;
#pragma unroll
    for (int j = 0; j < 16; ++j) {
      float4 v = W4[j];                                // per-lane, L2-resident
      float4 q0 = *(const float4*)&qs[0][4 * j];       // uniform addr -> broadcast
      float4 q1 = *(const float4*)&qs[1][4 * j];
      float4 q2 = *(const float4*)&qs[2][4 * j];
      float4 q3 = *(const float4*)&qs[3][4 * j];
      float4 q4 = *(const float4*)&qs[4][4 * j];
      float4 q5 = *(const float4*)&qs[5][4 * j];
      float4 q6 = *(const float4*)&qs[6][4 * j];
      float4 q7 = *(const float4*)&qs[7][4 * j];
      a0 += q0.x * v.x + q0.y * v.y + q0.z * v.z + q0.w * v.w;
      a1 += q1.x * v.x + q1.y * v.y + q1.z * v.z + q1.w * v.w;
      a2 += q2.x * v.x + q2.y * v.y + q2.z * v.z + q2.w * v.w;
      a3 += q3.x * v.x + q3.y * v.y + q3.z * v.z + q3.w * v.w;
      a4 += q4.x * v.x + q4.y * v.y + q4.z * v.z + q4.w * v.w;
      a5 += q5.x * v.x + q5.y * v.y + q5.z * v.z + q5.w * v.w;
      a6 += q6.x * v.x + q6.y * v.y + q6.z * v.z + q6.w * v.w;
      a7 += q7.x * v.x + q7.y * v.y + q7.z * v.z + q7.w * v.w;
    }
    float* dst = half ? Kh : Qh;
    const int h = e >> 4, d = e & 15;
    float* base = dst + (((size_t)(b * 4 + h) * PP) + ptile) * 16 + d;
    base[0 * 16] = a0; base[1 * 16] = a1; base[2 * 16] = a2; base[3 * 16] = a3;
    base[4 * 16] = a4; base[5 * 16] = a5; base[6 * 16] = a6; base[7 * 16] = a7;
  }
  grid.sync();

  // ---------------- P3: attention (verbatim) ----------------
  {
    const int b = blk >> 4;
    const int h = (blk >> 2) & 3;
    const int qq = blk & 3;
    const int sub = t & 7;
    const int rt = t >> 3;

    {
      const float4* src = (const float4*)(Kh + (size_t)(b * 4 + h) * PP * 16);
#pragma unroll
      for (int i = t; i < PP * 4; i += 256) {
        int k = i >> 2, j = i & 3;
        sm.at.sK[k * 5 + j] = src[i];
      }
      const float* yr = y + (b * PP + t) * 3;
      sm.at.sY[t] = make_float4(yr[0], yr[1], yr[2], 0.f);
    }
    __syncthreads();

    const int q0 = qq * 64 + rt * 2;
    const float4* q4 = (const float4*)(Qh + ((size_t)((b * 4 + h) * PP) + q0) * 16);
    float4 A0 = q4[0], A1 = q4[1], A2 = q4[2], A3 = q4[3];
    float4 B0 = q4[4], B1 = q4[5], B2 = q4[6], B3 = q4[7];

    float m0 = -INF_F, l0 = 0.f, x0 = 0.f, x1 = 0.f, x2 = 0.f;
    float m1 = -INF_F, l1 = 0.f, z0 = 0.f, z1 = 0.f, z2 = 0.f;

#pragma unroll 4
    for (int kk = 0; kk < 32; ++kk) {
      int k = kk * 8 + sub;
      float4 K0 = sm.at.sK[k * 5 + 0], K1 = sm.at.sK[k * 5 + 1];
      float4 K2 = sm.at.sK[k * 5 + 2], K3 = sm.at.sK[k * 5 + 3];
      float4 yv = sm.at.sY[k];
      float s0 = (A0.x*K0.x + A0.y*K0.y + A0.z*K0.z + A0.w*K0.w
                + A1.x*K1.x + A1.y*K1.y + A1.z*K1.z + A1.w*K1.w
                + A2.x*K2.x + A2.y*K2.y + A2.z*K2.z + A2.w*K2.w
                + A3.x*K3.x + A3.y*K3.y + A3.z*K3.z + A3.w*K3.w) * 0.25f;
      float s1 = (B0.x*K0.x + B0.y*K0.y + B0.z*K0.z + B0.w*K0.w
                + B1.x*K1.x + B1.y*K1.y + B1.z*K1.z + B1.w*K1.w
                + B2.x*K2.x + B2.y*K2.y + B2.z*K2.z + B2.w*K2.w
                + B3.x*K3.x + B3.y*K3.y + B3.z*K3.z + B3.w*K3.w) * 0.25f;
      {
        float mn = fmaxf(m0, s0);
        float p = __expf(s0 - mn), sc = __expf(m0 - mn);
        l0 = l0 * sc + p;
        x0 = x0 * sc + p * yv.x; x1 = x1 * sc + p * yv.y; x2 = x2 * sc + p * yv.z;
        m0 = mn;
      }
      {
        float mn = fmaxf(m1, s1);
        float p = __expf(s1 - mn), sc = __expf(m1 - mn);
        l1 = l1 * sc + p;
        z0 = z0 * sc + p * yv.x; z1 = z1 * sc + p * yv.y; z2 = z2 * sc + p * yv.z;
        m1 = mn;
      }
    }

#pragma unroll
    for (int off = 1; off < 8; off <<= 1) {
      float mo = __shfl_xor(m0, off), lo = __shfl_xor(l0, off);
      float c0 = __shfl_xor(x0, off), c1 = __shfl_xor(x1, off), c2 = __shfl_xor(x2, off);
      float M = fmaxf(m0, mo);
      float es = __expf(m0 - M), eo = __expf(mo - M);
      l0 = l0 * es + lo * eo;
      x0 = x0 * es + c0 * eo; x1 = x1 * es + c1 * eo; x2 = x2 * es + c2 * eo;
      m0 = M;

      float mo1 = __shfl_xor(m1, off), lo1 = __shfl_xor(l1, off);
      float e0 = __shfl_xor(z0, off), e1 = __shfl_xor(z1, off), e2 = __shfl_xor(z2, off);
      float M1 = fmaxf(m1, mo1);
      float es1 = __expf(m1 - M1), eo1 = __expf(mo1 - M1);
      l1 = l1 * es1 + lo1 * eo1;
      z0 = z0 * es1 + e0 * eo1; z1 = z1 * es1 + e1 * eo1; z2 = z2 * es1 + e2 * eo1;
      m1 = M1;
    }

    if (sub == 0) {
      float inv0 = 0.25f / l0;
      float inv1 = 0.25f / l1;
      float* o0 = y2 + (size_t)(b * PP + q0) * 4;
      atomicAdd(o0 + 0, x0 * inv0);
      atomicAdd(o0 + 1, x1 * inv0);
      atomicAdd(o0 + 2, x2 * inv0);
      float* o1 = o0 + 4;
      atomicAdd(o1 + 0, z0 * inv1);
      atomicAdd(o1 + 1, z1 * inv1);
      atomicAdd(o1 + 2, z2 * inv1);
    }
  }
  grid.sync();

  // ---------------- P4: interp + store (4 batch-groups per block) ----------------
  {
    const int m = blk * 256 + t;
    const float4 w = wB4[m];
    const int4 ix = idxB4[m];
    const float4* y4 = (const float4*)y2;

    for (int bg = 0; bg < 4; ++bg) {
      __syncthreads();                                 // protect sy from prev readers
      const float4* src = y4 + bg * 8 * PP;
#pragma unroll
      for (int j = 0; j < 8; ++j) sm.ip.sy[t + 256 * j] = src[t + 256 * j];
      __syncthreads();

#pragma unroll
      for (int i = 0; i < 8; ++i) {
        const float4* yb = sm.ip.sy + i * PP;
        float4 r0 = yb[ix.x];
        float4 r1 = yb[ix.y];
        float4 r2 = yb[ix.z];
        float3 res;
        res.x = (w.x * r0.x + w.y * r1.x + w.z * r2.x) * w.w;
        res.y = (w.x * r0.y + w.y * r1.y + w.z * r2.y) * w.w;
        res.z = (w.x * r0.z + w.y * r1.z + w.z * r2.z) * w.w;
        const int b = bg * 8 + i;
        *(float3*)(out + ((size_t)b * NM + m) * 3) = res;
      }
    }
  }
}

extern "C" void kernel_launch(void* const* d_in, const int* in_sizes, int n_in,
                              void* d_out, int out_size, void* d_ws, size_t ws_size,
                              hipStream_t stream) {
  const float* node  = (const float*)d_in[0];
  const float* mesh  = (const float*)d_in[1];
  const float* piv   = (const float*)d_in[2];
  const float* gamma = (const float*)d_in[3];
  const float* beta  = (const float*)d_in[4];
  const float* Wf    = (const float*)d_in[5];
  const float* bf    = (const float*)d_in[6];
  const float* Wp    = (const float*)d_in[7];
  const float* bp    = (const float*)d_in[8];
  const float* ipw   = (const float*)d_in[9];
  const float* ipb   = (const float*)d_in[10];
  float* out = (float*)d_out;
  float* ws = (float*)d_ws;

  void* args[] = {
    (void*)&node, (void*)&mesh, (void*)&piv, (void*)&gamma, (void*)&beta,
    (void*)&Wf, (void*)&bf, (void*)&Wp, (void*)&bp, (void*)&ipw, (void*)&ipb,
    (void*)&out, (void*)&ws
  };
  hipLaunchCooperativeKernel((void*)mega, dim3(512), dim3(256), args, 0, stream);
}

// Round 10
// 183.496 us; speedup vs baseline: 2.5702x; 2.5702x over previous
//
#include <hip/hip_runtime.h>
#include <math.h>

#define NM 131072
#define PP 256
#define BB 32
#define INF_F 3.0e38f

// mesh grid: 64x64 cells over [0,1)^2, expected 32 pts/cell
#define GM   64
#define GM2  (GM * GM)
#define CAPM 96
// pivot grid: 16x16 cells, expected 1 pivot/cell
#define GP   16
#define GP2  (GP * GP)
#define CAPP 8

typedef unsigned long long u64;

// Packed key: (float-bits of d << 32) | idx. d >= 0 so u32(d) ordering == float
// ordering; u64 ascending == (d asc, idx asc) == exact lax.top_k tie-break.
__device__ __forceinline__ u64 packkey(float d, int i) {
  return ((u64)__float_as_uint(d) << 32) | (unsigned)i;
}

// Branchless sorted insert into (k0<=k1<=k2).
__device__ __forceinline__ void ins3k(u64 k, u64& k0, u64& k1, u64& k2) {
  bool l0 = k < k0, l1 = k < k1, l2 = k < k2;
  k2 = l1 ? k1 : (l2 ? k : k2);
  k1 = l0 ? k0 : (l1 ? k : k1);
  k0 = l0 ? k : k0;
}

// Exact-fp32 distance matching the reference's (a-b)^2 + (c-d)^2 (no fma contraction).
__device__ __forceinline__ float dist2(float ax, float ay, float bx, float by) {
  float dx = ax - bx, dy = ay - by;
  return __fadd_rn(__fmul_rn(dx, dx), __fmul_rn(dy, dy));
}

// ---------- build: bucket mesh pts (64x64) + pivots (16x16) + zero y2 ----------
// Overflow lists are worst-case sized => bucketing is unconditionally exact.
__global__ __launch_bounds__(256)
void build_buckets(const float* __restrict__ mesh, const float* __restrict__ piv,
                   unsigned* __restrict__ cntM, unsigned* __restrict__ cntP,
                   unsigned* __restrict__ ovfc,  // [0]=mesh ovf count, [1]=pivot ovf count
                   float* __restrict__ bufM,     // [GM2][CAPM][3] = x,y,bitcast(idx)
                   int* __restrict__ bufP,       // [GP2][CAPP]
                   float* __restrict__ ovfM, int* __restrict__ ovfP,
                   float* __restrict__ y2) {
  const int g = blockIdx.x * 256 + threadIdx.x;
  if (g < NM) {
    float2 mp = ((const float2*)mesh)[g];
    int cx = min((int)(mp.x * GM), GM - 1);
    int cy = min((int)(mp.y * GM), GM - 1);
    int c = cy * GM + cx;
    unsigned s = atomicAdd(&cntM[c], 1u);
    if (s < CAPM) {
      float* d = bufM + (size_t)(c * CAPM + s) * 3;
      d[0] = mp.x; d[1] = mp.y; ((int*)d)[2] = g;
    } else {
      unsigned o = atomicAdd(&ovfc[0], 1u);   // ovfM sized NM: can never drop
      float* d = ovfM + (size_t)o * 3;
      d[0] = mp.x; d[1] = mp.y; ((int*)d)[2] = g;
    }
  }
  if (blockIdx.x == 0 && threadIdx.x < PP) {
    const int p = threadIdx.x;
    float2 pv = ((const float2*)piv)[p];
    int cx = min((int)(pv.x * GP), GP - 1);
    int cy = min((int)(pv.y * GP), GP - 1);
    int c = cy * GP + cx;
    unsigned s = atomicAdd(&cntP[c], 1u);
    if (s < CAPP) bufP[c * CAPP + s] = p;
    else { unsigned o = atomicAdd(&ovfc[1], 1u); ovfP[o] = p; }  // ovfP sized PP
  }
  if (blockIdx.x == 1) {  // zero y2 (float4-padded rows) for attn's atomics
    for (int j = threadIdx.x; j < BB * PP * 4; j += 256) y2[j] = 0.f;
  }
}

// LDS union for the merged KNN kernel (max 11 KB -> good occupancy).
union KnnSMem {
  struct { u64 sk[PP * 3]; u64 g3[3]; int sdone; } a;                             // knnA
  struct { float spx[PP], spy[PP]; unsigned scnt[GP2]; int sbuf[GP2 * CAPP]; } b; // knnB
};

// ---------- merged KNN: blocks 0-255 knnA (per pivot), 256-767 knnB (per m-tile) ----------
// R9 post-mortem: cooperative mega = 350 us of sync machinery -> reverted to
// multi-dispatch. knnA and knnB are independent (both read only build output),
// so one union-grid launch runs them concurrently and saves a dispatch.
__global__ __launch_bounds__(256)
void knn_union(const float* __restrict__ mesh, const float* __restrict__ piv,
               const unsigned* __restrict__ cntM, const float* __restrict__ bufM,
               const unsigned* __restrict__ cntP, const int* __restrict__ bufP,
               const unsigned* __restrict__ ovfc, const float* __restrict__ ovfM,
               const int* __restrict__ ovfP,
               float* __restrict__ wA, int* __restrict__ idxA,
               float4* __restrict__ wB4, int4* __restrict__ idxB4) {
  const int blk = blockIdx.x;
  const int t = threadIdx.x;
  __shared__ KnnSMem sm;

  if (blk < 256) {
    // ---- knnA: block = pivot; ring search over mesh grid; block-reduce ----
    // Exactness: after rings 0..R, unscanned points are >= R*cell away. Stop
    // only when (R*cell)^2 > d2 (strict). NaN d2 (<3 found) => keep expanding.
    const int p = blk;
    const float2 pv = ((const float2*)piv)[p];
    const int cx = min((int)(pv.x * GM), GM - 1);
    const int cy = min((int)(pv.y * GM), GM - 1);

    u64 b0 = ~0ull, b1 = ~0ull, b2 = ~0ull;
    {
      int x0 = max(cx - 1, 0), x1 = min(cx + 1, GM - 1);
      int y0 = max(cy - 1, 0), y1 = min(cy + 1, GM - 1);
      for (int yy = y0; yy <= y1; ++yy) {
        int cb = yy * GM + x0;
        int tot = (x1 - x0 + 1) * CAPM;
        for (int s = t; s < tot; s += 256) {
          int ci = s / CAPM, j = s - ci * CAPM;
          int c = cb + ci;
          if (j < (int)min(cntM[c], (unsigned)CAPM)) {
            const float* cp = bufM + (size_t)(c * CAPM + j) * 3;
            float d = dist2(pv.x, pv.y, cp[0], cp[1]);
            ins3k(packkey(d, ((const int*)cp)[2]), b0, b1, b2);
          }
        }
      }
      int no = (int)ovfc[0];                      // usually 0
      for (int j = t; j < no; j += 256) {
        const float* cp = ovfM + (size_t)j * 3;
        float d = dist2(pv.x, pv.y, cp[0], cp[1]);
        ins3k(packkey(d, ((const int*)cp)[2]), b0, b1, b2);
      }
    }

    int R = 1;
    u64 p0 = ~0ull, p1 = ~0ull, p2 = ~0ull;      // carried global best (merged by t0)
    while (true) {
      sm.a.sk[t * 3 + 0] = b0; sm.a.sk[t * 3 + 1] = b1; sm.a.sk[t * 3 + 2] = b2;
      __syncthreads();
      if (t < 32) {
        u64 e0 = ~0ull, e1 = ~0ull, e2 = ~0ull;
#pragma unroll
        for (int s = 0; s < 8; ++s) {
          int o = (t + 32 * s) * 3;
          ins3k(sm.a.sk[o], e0, e1, e2); ins3k(sm.a.sk[o + 1], e0, e1, e2); ins3k(sm.a.sk[o + 2], e0, e1, e2);
        }
        sm.a.sk[t * 3] = e0; sm.a.sk[t * 3 + 1] = e1; sm.a.sk[t * 3 + 2] = e2;
      }
      __syncthreads();
      if (t == 0) {
        u64 e0 = p0, e1 = p1, e2 = p2;
        for (int s = 0; s < 32; ++s) {
          ins3k(sm.a.sk[s * 3], e0, e1, e2); ins3k(sm.a.sk[s * 3 + 1], e0, e1, e2); ins3k(sm.a.sk[s * 3 + 2], e0, e1, e2);
        }
        sm.a.g3[0] = e0; sm.a.g3[1] = e1; sm.a.g3[2] = e2;
        float d2f = __uint_as_float((unsigned)(e2 >> 32));
        float md = (float)R * (1.0f / GM);
        sm.a.sdone = (md * md > d2f) ? 1 : 0;    // NaN => false => expand
      }
      __syncthreads();
      if (sm.a.sdone) break;
      p0 = sm.a.g3[0]; p1 = sm.a.g3[1]; p2 = sm.a.g3[2];
      b0 = b1 = b2 = ~0ull;
      R += 1;
      int x0 = max(cx - R, 0), x1 = min(cx + R, GM - 1);
      for (int pass = 0; pass < 2; ++pass) {
        int yy = pass ? cy + R : cy - R;
        if (yy < 0 || yy > GM - 1) continue;
        int cb = yy * GM + x0;
        int tot = (x1 - x0 + 1) * CAPM;
        for (int s = t; s < tot; s += 256) {
          int ci = s / CAPM, j = s - ci * CAPM;
          int c = cb + ci;
          if (j < (int)min(cntM[c], (unsigned)CAPM)) {
            const float* cp = bufM + (size_t)(c * CAPM + j) * 3;
            float d = dist2(pv.x, pv.y, cp[0], cp[1]);
            ins3k(packkey(d, ((const int*)cp)[2]), b0, b1, b2);
          }
        }
      }
      int yy0 = max(cy - R + 1, 0), yy1 = min(cy + R - 1, GM - 1);
      for (int pass = 0; pass < 2; ++pass) {
        int xx = pass ? cx + R : cx - R;
        if (xx < 0 || xx > GM - 1) continue;
        int tot = (yy1 - yy0 + 1) * CAPM;
        for (int s = t; s < tot; s += 256) {
          int ri = s / CAPM, j = s - ri * CAPM;
          int c = (yy0 + ri) * GM + xx;
          if (j < (int)min(cntM[c], (unsigned)CAPM)) {
            const float* cp = bufM + (size_t)(c * CAPM + j) * 3;
            float d = dist2(pv.x, pv.y, cp[0], cp[1]);
            ins3k(packkey(d, ((const int*)cp)[2]), b0, b1, b2);
          }
        }
      }
      __syncthreads();
    }
    if (t == 0) {
#pragma unroll
      for (int k = 0; k < 3; ++k) {
        u64 e = sm.a.g3[k];
        float d = __uint_as_float((unsigned)(e >> 32));
        wA[p * 3 + k] = 1.0f / fmaxf(d, 1e-16f);
        idxA[p * 3 + k] = (int)(unsigned)(e & 0xffffffffu);
      }
    }
  } else {
    // ---- knnB: per-thread ring search over pivot grid; packed outputs ----
    {
      float2 pvv = ((const float2*)piv)[t];
      sm.b.spx[t] = pvv.x; sm.b.spy[t] = pvv.y;
      sm.b.scnt[t] = cntP[t];
      for (int j = t; j < GP2 * CAPP; j += 256) sm.b.sbuf[j] = bufP[j];
    }
    __syncthreads();

    const int m = (blk - 256) * 256 + t;
    const float2 mv = ((const float2*)mesh)[m];
    const int cx = min((int)(mv.x * GP), GP - 1);
    const int cy = min((int)(mv.y * GP), GP - 1);
    u64 k0 = ~0ull, k1 = ~0ull, k2 = ~0ull;

    {  // rings 0..2 (5x5 clamped)
      int x0 = max(cx - 2, 0), x1 = min(cx + 2, GP - 1);
      int y0 = max(cy - 2, 0), y1 = min(cy + 2, GP - 1);
      for (int yy = y0; yy <= y1; ++yy)
        for (int xx = x0; xx <= x1; ++xx) {
          int c = yy * GP + xx;
          int n = (int)min(sm.b.scnt[c], (unsigned)CAPP);
          for (int j = 0; j < n; ++j) {
            int qq = sm.b.sbuf[c * CAPP + j];
            float d = dist2(mv.x, mv.y, sm.b.spx[qq], sm.b.spy[qq]);
            ins3k(packkey(d, qq), k0, k1, k2);
          }
        }
      int no = (int)ovfc[1];                     // usually 0
      for (int j = 0; j < no; ++j) {
        int qq = ovfP[j];
        float d = dist2(mv.x, mv.y, sm.b.spx[qq], sm.b.spy[qq]);
        ins3k(packkey(d, qq), k0, k1, k2);
      }
    }
    int R = 2;
    while (true) {
      float d2f = __uint_as_float((unsigned)(k2 >> 32));
      float md = (float)R * (1.0f / GP);
      if (md * md > d2f) break;                  // NaN => expand
      R += 1;
      if (R >= 2 * GP) break;                    // whole grid covered (safety)
      int x0 = max(cx - R, 0), x1 = min(cx + R, GP - 1);
      for (int pass = 0; pass < 2; ++pass) {
        int yy = pass ? cy + R : cy - R;
        if (yy < 0 || yy > GP - 1) continue;
        for (int xx = x0; xx <= x1; ++xx) {
          int c = yy * GP + xx;
          int n = (int)min(sm.b.scnt[c], (unsigned)CAPP);
          for (int j = 0; j < n; ++j) {
            int qq = sm.b.sbuf[c * CAPP + j];
            float d = dist2(mv.x, mv.y, sm.b.spx[qq], sm.b.spy[qq]);
            ins3k(packkey(d, qq), k0, k1, k2);
          }
        }
      }
      int yy0 = max(cy - R + 1, 0), yy1 = min(cy + R - 1, GP - 1);
      for (int pass = 0; pass < 2; ++pass) {
        int xx = pass ? cx + R : cx - R;
        if (xx < 0 || xx > GP - 1) continue;
        for (int yy = yy0; yy <= yy1; ++yy) {
          int c = yy * GP + xx;
          int n = (int)min(sm.b.scnt[c], (unsigned)CAPP);
          for (int j = 0; j < n; ++j) {
            int qq = sm.b.sbuf[c * CAPP + j];
            float d = dist2(mv.x, mv.y, sm.b.spx[qq], sm.b.spy[qq]);
            ins3k(packkey(d, qq), k0, k1, k2);
          }
        }
      }
    }

    float d0 = __uint_as_float((unsigned)(k0 >> 32));
    float d1 = __uint_as_float((unsigned)(k1 >> 32));
    float d2v = __uint_as_float((unsigned)(k2 >> 32));
    float w0 = 1.0f / fmaxf(d0, 1e-16f);
    float w1 = 1.0f / fmaxf(d1, 1e-16f);
    float w2 = 1.0f / fmaxf(d2v, 1e-16f);
    float inv = 1.0f / (w0 + w1 + w2);
    wB4[m] = make_float4(w0, w1, w2, inv);
    idxB4[m] = make_int4((int)(unsigned)(k0 & 0xffffffffu),
                         (int)(unsigned)(k1 & 0xffffffffu),
                         (int)(unsigned)(k2 & 0xffffffffu), 0);
  }
}

// ---------- fused gather+LN+interp + q/Q/K projection ----------
// __launch_bounds__(128, 2): VGPR budget 256/wave so wreg[64] stays in registers.
__global__ __launch_bounds__(128, 2)
void gather_qqk(const float* __restrict__ node, const float* __restrict__ piv,
                const float* __restrict__ gamma, const float* __restrict__ beta,
                const float* __restrict__ Wf, const float* __restrict__ bf,
                const float* __restrict__ Wp, const float* __restrict__ bp,
                const float* __restrict__ ipw, const float* __restrict__ ipb,
                const float* __restrict__ wA, const int* __restrict__ idxA,
                float* __restrict__ y, float* __restrict__ Qh, float* __restrict__ Kh) {
  const int b = blockIdx.x >> 5;
  const int ptile = (blockIdx.x & 31) * 8;
  const int t = threadIdx.x;
  __shared__ float qs[8][64];
  __shared__ float ys[8][3];

  if (t < 8) {
    const int p = ptile + t;
    const float g0 = gamma[0], g1 = gamma[1], g2 = gamma[2];
    const float be0 = beta[0], be1 = beta[1], be2 = beta[2];
    float num0 = 0.f, num1 = 0.f, num2 = 0.f, den = 0.f;
#pragma unroll
    for (int k = 0; k < 3; ++k) {
      int idx = idxA[p * 3 + k];
      float w = wA[p * 3 + k];
      const float* r = node + ((size_t)b * NM + idx) * 3;
      float a0 = r[0], a1 = r[1], a2 = r[2];
      float mu = (a0 + a1 + a2) * (1.0f / 3.0f);
      float e0 = a0 - mu, e1 = a1 - mu, e2 = a2 - mu;
      float var = (e0 * e0 + e1 * e1 + e2 * e2) * (1.0f / 3.0f);
      float sc = 1.0f / sqrtf(var + 1e-5f);
      num0 += (e0 * sc * g0 + be0) * w;
      num1 += (e1 * sc * g1 + be1) * w;
      num2 += (e2 * sc * g2 + be2) * w;
      den += w;
    }
    float o0 = num0 / den, o1 = num1 / den, o2 = num2 / den;
    ys[t][0] = o0; ys[t][1] = o1; ys[t][2] = o2;
    float* yr = y + (b * PP + p) * 3;
    yr[0] = o0; yr[1] = o1; yr[2] = o2;   // attn stages y from global
  }
  __syncthreads();

  const int e = t & 63;
  const int half = t >> 6;  // 0 -> Q, 1 -> K
  {
    float wf0 = Wf[e * 3], wf1 = Wf[e * 3 + 1], wf2 = Wf[e * 3 + 2];
    float wp0 = Wp[e * 2], wp1 = Wp[e * 2 + 1];
    float cst = bf[e] + bp[e];
    for (int r = half; r < 8; r += 2) {
      int p = ptile + r;
      float pe = piv[2 * p] * wp0 + piv[2 * p + 1] * wp1;
      qs[r][e] = ys[r][0] * wf0 + ys[r][1] * wf1 + ys[r][2] * wf2 + cst + pe;
    }
  }
  __syncthreads();

  const int row = half * 64 + e;
  float wreg[64];
  const float4* W4 = (const float4*)(ipw + row * 64);
#pragma unroll
  for (int j = 0; j < 16; ++j) {
    float4 v = W4[j];
    wreg[4 * j] = v.x; wreg[4 * j + 1] = v.y; wreg[4 * j + 2] = v.z; wreg[4 * j + 3] = v.w;
  }
  float bias = ipb[row];
  float* dst = half ? Kh : Qh;
  const int h = e >> 4, d = e & 15;
  for (int r = 0; r < 8; ++r) {
    float acc = bias;
#pragma unroll
    for (int j = 0; j < 64; ++j) acc += qs[r][j] * wreg[j];
    int p = ptile + r;
    dst[(((b * 4 + h) * PP) + p) * 16 + d] = acc;
  }
}

// ---------- attention: 512 blocks, 64 q-rows/block; y2 rows float4-padded ----------
__global__ __launch_bounds__(256, 2)
void attn_kernel(const float* __restrict__ Qh, const float* __restrict__ Kh,
                 const float* __restrict__ y, float* __restrict__ y2) {
  const int b = blockIdx.x >> 4;
  const int h = (blockIdx.x >> 2) & 3;
  const int qq = blockIdx.x & 3;
  const int t = threadIdx.x;          // 256 threads
  const int sub = t & 7;              // k-chain id
  const int rt = t >> 3;              // 0..31 row-pair id

  __shared__ float4 sK[PP * 5];       // 20 KB, stride-5 f4 rows
  __shared__ float4 sY[PP];           // 4 KB

  {
    const float4* src = (const float4*)(Kh + (size_t)(b * 4 + h) * PP * 16);
#pragma unroll
    for (int i = t; i < PP * 4; i += 256) {
      int k = i >> 2, j = i & 3;
      sK[k * 5 + j] = src[i];
    }
    const float* yr = y + (b * PP + t) * 3;
    sY[t] = make_float4(yr[0], yr[1], yr[2], 0.f);
  }
  __syncthreads();

  const int q0 = qq * 64 + rt * 2;
  const float4* q4 = (const float4*)(Qh + ((size_t)((b * 4 + h) * PP) + q0) * 16);
  float4 A0 = q4[0], A1 = q4[1], A2 = q4[2], A3 = q4[3];   // row q0
  float4 B0 = q4[4], B1 = q4[5], B2 = q4[6], B3 = q4[7];   // row q0+1

  float m0 = -INF_F, l0 = 0.f, x0 = 0.f, x1 = 0.f, x2 = 0.f;
  float m1 = -INF_F, l1 = 0.f, z0 = 0.f, z1 = 0.f, z2 = 0.f;

#pragma unroll 4
  for (int kk = 0; kk < 32; ++kk) {
    int k = kk * 8 + sub;
    float4 K0 = sK[k * 5 + 0], K1 = sK[k * 5 + 1], K2 = sK[k * 5 + 2], K3 = sK[k * 5 + 3];
    float4 yv = sY[k];
    float s0 = (A0.x*K0.x + A0.y*K0.y + A0.z*K0.z + A0.w*K0.w
              + A1.x*K1.x + A1.y*K1.y + A1.z*K1.z + A1.w*K1.w
              + A2.x*K2.x + A2.y*K2.y + A2.z*K2.z + A2.w*K2.w
              + A3.x*K3.x + A3.y*K3.y + A3.z*K3.z + A3.w*K3.w) * 0.25f;
    float s1 = (B0.x*K0.x + B0.y*K0.y + B0.z*K0.z + B0.w*K0.w
              + B1.x*K1.x + B1.y*K1.y + B1.z*K1.z + B1.w*K1.w
              + B2.x*K2.x + B2.y*K2.y + B2.z*K2.z + B2.w*K2.w
              + B3.x*K3.x + B3.y*K3.y + B3.z*K3.z + B3.w*K3.w) * 0.25f;
    {
      float mn = fmaxf(m0, s0);
      float p = __expf(s0 - mn), sc = __expf(m0 - mn);
      l0 = l0 * sc + p;
      x0 = x0 * sc + p * yv.x; x1 = x1 * sc + p * yv.y; x2 = x2 * sc + p * yv.z;
      m0 = mn;
    }
    {
      float mn = fmaxf(m1, s1);
      float p = __expf(s1 - mn), sc = __expf(m1 - mn);
      l1 = l1 * sc + p;
      z0 = z0 * sc + p * yv.x; z1 = z1 * sc + p * yv.y; z2 = z2 * sc + p * yv.z;
      m1 = mn;
    }
  }

  // butterfly merge of the 8 k-chain partials (lanes differing in bits 0..2)
#pragma unroll
  for (int off = 1; off < 8; off <<= 1) {
    float mo = __shfl_xor(m0, off), lo = __shfl_xor(l0, off);
    float b0 = __shfl_xor(x0, off), b1 = __shfl_xor(x1, off), b2 = __shfl_xor(x2, off);
    float M = fmaxf(m0, mo);
    float es = __expf(m0 - M), eo = __expf(mo - M);
    l0 = l0 * es + lo * eo;
    x0 = x0 * es + b0 * eo; x1 = x1 * es + b1 * eo; x2 = x2 * es + b2 * eo;
    m0 = M;

    float mo1 = __shfl_xor(m1, off), lo1 = __shfl_xor(l1, off);
    float c0 = __shfl_xor(z0, off), c1 = __shfl_xor(z1, off), c2 = __shfl_xor(z2, off);
    float M1 = fmaxf(m1, mo1);
    float es1 = __expf(m1 - M1), eo1 = __expf(mo1 - M1);
    l1 = l1 * es1 + lo1 * eo1;
    z0 = z0 * es1 + c0 * eo1; z1 = z1 * es1 + c1 * eo1; z2 = z2 * es1 + c2 * eo1;
    m1 = M1;
  }

  if (sub == 0) {
    float inv0 = 0.25f / l0;          // mean over 4 heads
    float inv1 = 0.25f / l1;
    float* o0 = y2 + (size_t)(b * PP + q0) * 4;   // float4-padded row
    atomicAdd(o0 + 0, x0 * inv0);
    atomicAdd(o0 + 1, x1 * inv0);
    atomicAdd(o0 + 2, x2 * inv0);
    float* o1 = o0 + 4;
    atomicAdd(o1 + 0, z0 * inv1);
    atomicAdd(o1 + 1, z1 * inv1);
    atomicAdd(o1 + 2, z2 * inv1);
  }
}

// ---------- pure interp: LDS-staged y2 slice, gathers on the LDS pipe ----------
__global__ __launch_bounds__(256)
void interp_out(const float4* __restrict__ y2, const float4* __restrict__ wB4,
                const int4* __restrict__ idxB4, float* __restrict__ out) {
  const int t = threadIdx.x;
  const int mt = blockIdx.x >> 2;     // m-tile
  const int bg = blockIdx.x & 3;      // batch-group (8 batches)
  __shared__ float4 sy[8 * PP];       // 32 KB
  {
    const float4* src = y2 + bg * 8 * PP;
#pragma unroll
    for (int j = 0; j < 8; ++j) sy[t + 256 * j] = src[t + 256 * j];
  }
  __syncthreads();

  const int m = mt * 256 + t;
  const float4 w = wB4[m];
  const int4 ix = idxB4[m];

#pragma unroll
  for (int i = 0; i < 8; ++i) {
    const float4* yb = sy + i * PP;
    float4 r0 = yb[ix.x];
    float4 r1 = yb[ix.y];
    float4 r2 = yb[ix.z];
    float3 res;
    res.x = (w.x * r0.x + w.y * r1.x + w.z * r2.x) * w.w;
    res.y = (w.x * r0.y + w.y * r1.y + w.z * r2.y) * w.w;
    res.z = (w.x * r0.z + w.y * r1.z + w.z * r2.z) * w.w;
    const int b = bg * 8 + i;                    // wave-uniform
    *(float3*)(out + ((size_t)b * NM + m) * 3) = res;  // lane-contiguous 12 B
  }
}

extern "C" void kernel_launch(void* const* d_in, const int* in_sizes, int n_in,
                              void* d_out, int out_size, void* d_ws, size_t ws_size,
                              hipStream_t stream) {
  const float* node  = (const float*)d_in[0];
  const float* mesh  = (const float*)d_in[1];
  const float* piv   = (const float*)d_in[2];
  const float* gamma = (const float*)d_in[3];
  const float* beta  = (const float*)d_in[4];
  const float* Wf    = (const float*)d_in[5];
  const float* bf    = (const float*)d_in[6];
  const float* Wp    = (const float*)d_in[7];
  const float* bp    = (const float*)d_in[8];
  const float* ipw   = (const float*)d_in[9];
  const float* ipb   = (const float*)d_in[10];
  float* out = (float*)d_out;

  // workspace layout (4-byte units; all block bases 16B-aligned)
  unsigned* cntM = (unsigned*)d_ws;                   // 4096
  unsigned* cntP = cntM + 4096;                       // 256
  unsigned* ovfc = cntP + 256;                        // 2 (pad to 4608 total)
  float* bufM = (float*)d_ws + 4608;                  // GM2*CAPM*3 = 1179648
  int*   bufP = (int*)(bufM + (size_t)GM2 * CAPM * 3);// 2048
  float* ovfM = (float*)(bufP + GP2 * CAPP);          // NM*3 (worst-case overflow)
  int*   ovfP = (int*)(ovfM + (size_t)NM * 3);        // 256
  float* wA   = (float*)(ovfP + PP);                  // 768
  int*   idxA = (int*)(wA + PP * 3);                  // 768
  float* y    = (float*)(idxA + PP * 3);              // BB*PP*3
  float* Qh   = y + BB * PP * 3;                      // BB*4*PP*16
  float* Kh   = Qh + BB * PP * 64;
  float* y2   = Kh + BB * PP * 64;                    // BB*PP*4 (float4-padded rows)
  float4* wB4   = (float4*)(y2 + BB * PP * 4);        // NM float4
  int4*   idxB4 = (int4*)(wB4 + NM);                  // NM int4

  hipMemsetAsync(cntM, 0, 4608 * sizeof(unsigned), stream);
  build_buckets<<<NM / 256, 256, 0, stream>>>(mesh, piv, cntM, cntP, ovfc,
                                              bufM, bufP, ovfM, ovfP, y2);
  knn_union<<<256 + NM / 256, 256, 0, stream>>>(mesh, piv, cntM, bufM, cntP, bufP,
                                                ovfc, ovfM, ovfP, wA, idxA, wB4, idxB4);
  gather_qqk<<<BB * 32, 128, 0, stream>>>(node, piv, gamma, beta, Wf, bf, Wp, bp, ipw, ipb,
                                          wA, idxA, y, Qh, Kh);
  attn_kernel<<<BB * 4 * 4, 256, 0, stream>>>(Qh, Kh, y, y2);
  interp_out<<<NM / 256 * 4, 256, 0, stream>>>((const float4*)y2, wB4, idxB4, out);
}